// Round 12
// baseline (502.510 us; speedup 1.0000x reference)
//
#include <hip/hip_runtime.h>

namespace {
constexpr int CC = 3, FF = 51;
constexpr int BB = 4;
constexpr int HOUT = 384, WOUT = 384;
constexpr int HIN = 434, WIN = 434;
constexpr int KY = 4;                 // vertical outputs per thread
constexpr int LANES = 64;             // x-pixels per block
constexpr int NW = 4;                 // fx-split waves per block (13/13/13/12 taps)
constexpr int EXT = LANES + FF - 1;   // 114 valid f16 per channel strip
constexpr int LPAD = 128;             // strip pitch (f16), pow2 -> static indices
constexpr int NSG = CC * LPAD / LANES;   // 6 staged elems/lane
constexpr int NQW = 4;                // b64 LDS reads per (c, step)
constexpr int NPW = 8;                // f16 pairs per (t, step)
constexpr int SSTRIDE = NW * CC * LPAD;  // u16 elems per LDS buffer (1536)

using half2v = _Float16 __attribute__((ext_vector_type(2)));

// r4/r6-proven: __builtin_amdgcn_fdot2 emits v_dot2_f32_f16.
// (r5 lesson: hand-written VOP3P asm broke numerics — keep the builtin.)
__device__ __forceinline__ float fdot2f(half2v a, half2v b, float c) {
#if __has_builtin(__builtin_amdgcn_fdot2)
  return __builtin_amdgcn_fdot2(a, b, c, false);
#else
  return c + (float)a.x * (float)b.x + (float)a.y * (float)b.y;
#endif
}
}  // namespace

// Reg-staged In (precise register-tracked vmcnt — r11 lesson: global_load_lds
// forces compiler vmcnt(0) drains and cannot pipeline at HIP level).
// Ver prefetched in 4-step groups, double-buffered (vA/vB), issued one full
// group (~1200 cyc of dot2 issue) ahead of consumption.
__global__ __launch_bounds__(NW* LANES, 2) void sepconv_kernel(
    const float* __restrict__ In, const float* __restrict__ Ver,
    const float* __restrict__ Hor, float* __restrict__ Out) {
  const int lane = threadIdx.x;
  const int w = threadIdx.y;          // fx-quarter
  const int x0 = blockIdx.x * LANES;
  const int y0 = blockIdx.y * KY;
  const int b = blockIdx.z;
  const int x = x0 + lane;
  const int fxBase = 13 * w;          // taps [fxBase, fxBase+ntaps)
  const int ntaps = (w < 3) ? 13 : 12;
  const int aw = (lane + fxBase) & 3;        // alignment class
  const int bw = lane + fxBase - aw;         // 4-f16-aligned strip base elem

  __shared__ __align__(16) unsigned short sIn[2][NW][CC][LPAD];
  __shared__ float sRed[NW - 1][CC][KY][LANES];
  unsigned short* const sflat = &sIn[0][0][0][0];

  const size_t HW = (size_t)HOUT * WOUT;

  // ---- per-pixel horizontal taps for this wave's fx range (OOB -> 0)
  half2v hp[KY][NPW];
  {
    const float* horx = Hor + (size_t)b * FF * HW + x;
#pragma unroll
    for (int t = 0; t < KY; ++t) {
      const float* hb = horx + (size_t)(y0 + t) * WOUT;
#pragma unroll
      for (int j = 0; j < NPW; ++j) {
        const int u0 = 2 * j - aw;
        const int u1 = u0 + 1;
        float f0 = (u0 >= 0 && u0 < ntaps) ? hb[(size_t)(fxBase + u0) * HW] : 0.0f;
        float f1 = (u1 >= 0 && u1 < ntaps) ? hb[(size_t)(fxBase + u1) * HW] : 0.0f;
        half2v p;
        p.x = (_Float16)f0;  // RTE
        p.y = (_Float16)f1;
        hp[t][j] = p;
      }
    }
  }

  const float* inb = In + ((size_t)b * CC * HIN + y0) * WIN + x0;
  const float* verb = Ver + (size_t)b * FF * HW + (size_t)y0 * WOUT + x;
  const float* vbase0 = Ver + (size_t)b * FF * HW + (size_t)(y0 + 0) * WOUT + x0;
  const float* vbase1 = Ver + (size_t)b * FF * HW + (size_t)(y0 + 1) * WOUT + x0;
  const float* vbase2 = Ver + (size_t)b * FF * HW + (size_t)(y0 + 2) * WOUT + x0;
  const float* vbase3 = Ver + (size_t)b * FF * HW + (size_t)(y0 + 3) * WOUT + x0;

  float acc[CC][KY] = {};
  float sv[NSG];
  float vA[4 * KY], vB[4 * KY];  // two 4-step groups of Ver values

  // ---- In staging (r6-proven; register-tracked loads) ----
#define STAGE_LOAD(R)                                                         \
  _Pragma("unroll") for (int k = 0; k < NSG; ++k) {                           \
    const int e = lane + (k & 1) * 64;                                        \
    const bool valid = ((k & 1) == 0) || (lane < EXT - LANES);                \
    sv[k] = valid ? inb[(size_t)((k >> 1) * HIN + (R)) * WIN + e] : 0.0f;     \
  }

#define STAGE_WRITE(BF)                                                       \
  _Pragma("unroll") for (int k = 0; k < NSG; ++k) {                           \
    const int e = lane + (k & 1) * 64;                                        \
    sflat[(BF)*SSTRIDE + (w * CC + (k >> 1)) * LPAD + e] =                    \
        __builtin_bit_cast(unsigned short, (_Float16)sv[k]);                  \
  }

  // ---- Ver prefetch: steady 4-step burst (16 loads, uniform bases) ----
#define VV_S4(R, VS)                                                          \
  _Pragma("unroll") for (int s = 0; s < 4; ++s) {                             \
    VS[4 * s + 0] = vbase0[(size_t)((R) + s - 0) * HW + lane];                \
    VS[4 * s + 1] = vbase1[(size_t)((R) + s - 1) * HW + lane];                \
    VS[4 * s + 2] = vbase2[(size_t)((R) + s - 2) * HW + lane];                \
    VS[4 * s + 3] = vbase3[(size_t)((R) + s - 3) * HW + lane];                \
  }

  // guarded single-step load into slot S (R compile-time -> guards fold)
#define VV_G1(R, VS, S)                                                       \
  _Pragma("unroll") for (int t = 0; t < KY; ++t) {                            \
    const int u = (R)-t;                                                      \
    VS[4 * (S) + t] = (u >= 0 && u < FF)                                      \
                          ? verb[(size_t)u * HW + (size_t)t * WOUT]           \
                          : 0.0f;                                             \
  }

  // ---- dot core for one step; vv = VS[4*S + t] (all static indices) ----
#define COMPUTE(BF, VS, S)                                                    \
  {                                                                           \
    _Pragma("unroll") for (int c = 0; c < CC; ++c) {                          \
      const unsigned short* rp = sflat + (BF)*SSTRIDE + (w * CC + c) * LPAD + bw; \
      float d[KY];                                                            \
      {                                                                       \
        const uint2 u2 = *reinterpret_cast<const uint2*>(rp);                 \
        const half2v p0 = __builtin_bit_cast(half2v, u2.x);                   \
        const half2v p1 = __builtin_bit_cast(half2v, u2.y);                   \
        _Pragma("unroll") for (int t = 0; t < KY; ++t) {                      \
          d[t] = fdot2f(p0, hp[t][0], 0.0f);                                  \
          d[t] = fdot2f(p1, hp[t][1], d[t]);                                  \
        }                                                                     \
      }                                                                       \
      _Pragma("unroll") for (int q = 1; q < NQW; ++q) {                       \
        const uint2 u2 = *reinterpret_cast<const uint2*>(rp + 4 * q);         \
        const half2v p0 = __builtin_bit_cast(half2v, u2.x);                   \
        const half2v p1 = __builtin_bit_cast(half2v, u2.y);                   \
        _Pragma("unroll") for (int t = 0; t < KY; ++t) {                      \
          d[t] = fdot2f(p0, hp[t][2 * q], d[t]);                              \
          d[t] = fdot2f(p1, hp[t][2 * q + 1], d[t]);                          \
        }                                                                     \
      }                                                                       \
      _Pragma("unroll") for (int t = 0; t < KY; ++t)                          \
        acc[c][t] = __builtin_fmaf(d[t], VS[4 * (S) + t], acc[c][t]);         \
    }                                                                         \
  }

  // 4 steps, rows R..R+3; entry: buf0 holds row R; exit: buf0 holds row R+4
#define STEP4(R, VS)                                                          \
  STAGE_LOAD((R) + 1); COMPUTE(0, VS, 0); STAGE_WRITE(1);                     \
  STAGE_LOAD((R) + 2); COMPUTE(1, VS, 1); STAGE_WRITE(0);                     \
  STAGE_LOAD((R) + 3); COMPUTE(0, VS, 2); STAGE_WRITE(1);                     \
  STAGE_LOAD((R) + 4); COMPUTE(1, VS, 3); STAGE_WRITE(0);

  // ---- prologue: row 0 staged; vv group0 (guarded) + group1 (steady) ----
  STAGE_LOAD(0);
  STAGE_WRITE(0);
  VV_G1(0, vA, 0); VV_G1(1, vA, 1); VV_G1(2, vA, 2); VV_G1(3, vA, 3);
  VV_S4(4, vB);          // issue group 1 (steps 4..7) one group ahead
  STEP4(0, vA);          // steps 0..3

  // ---- steady: groups of 4 steps, vv sets ping-pong, issue 1 group ahead
#pragma unroll 1
  for (int r = 4; r < 44; r += 8) {
    VV_S4(r + 4, vA);    // steps r+4..r+7
    STEP4(r, vB);        // steps r..r+3
    VV_S4(r + 8, vB);    // steps r+8..r+11 (max 44..47, all rows valid)
    STEP4(r + 4, vA);    // steps r+4..r+7
  }
  // after loop: computed through step 43; vB holds steps 44..47

  // ---- tail: steps 44..53 (guarded vv at the fy edges) ----
  VV_G1(48, vA, 0); VV_G1(49, vA, 1); VV_G1(50, vA, 2); VV_G1(51, vA, 3);
  STEP4(44, vB);         // steps 44..47 (loads rows 45..48)
  VV_G1(52, vB, 0); VV_G1(53, vB, 1);
  STEP4(48, vA);         // steps 48..51 (loads rows 49..52; row 52 -> buf0)
  STAGE_LOAD(53);
  COMPUTE(0, vB, 0);     // step 52 (row 52 in buf0)
  STAGE_WRITE(1);
  COMPUTE(1, vB, 1);     // step 53 (row 53 in buf1)

  // ---- cross-wave fx reduction (4-way), then store
  if (w > 0) {
#pragma unroll
    for (int c = 0; c < CC; ++c)
#pragma unroll
      for (int t = 0; t < KY; ++t) sRed[w - 1][c][t][lane] = acc[c][t];
  }
  __syncthreads();
  if (w == 0) {
    float* outb = Out + (size_t)b * CC * HW + (size_t)y0 * WOUT + x0 + lane;
#pragma unroll
    for (int c = 0; c < CC; ++c)
#pragma unroll
      for (int t = 0; t < KY; ++t)
        outb[(size_t)c * HW + (size_t)t * WOUT] =
            acc[c][t] + sRed[0][c][t][lane] + sRed[1][c][t][lane] +
            sRed[2][c][t][lane];
  }
#undef STAGE_LOAD
#undef STAGE_WRITE
#undef VV_S4
#undef VV_G1
#undef COMPUTE
#undef STEP4
}

extern "C" void kernel_launch(void* const* d_in, const int* in_sizes, int n_in,
                              void* d_out, int out_size, void* d_ws, size_t ws_size,
                              hipStream_t stream) {
  const float* In = (const float*)d_in[0];
  const float* Ver = (const float*)d_in[1];
  const float* Hor = (const float*)d_in[2];
  float* Out = (float*)d_out;

  dim3 grid(WOUT / LANES, HOUT / KY, BB);
  dim3 block(LANES, NW, 1);
  sepconv_kernel<<<grid, block, 0, stream>>>(In, Ver, Hor, Out);
}

// Round 13
// 415.852 us; speedup vs baseline: 1.2084x; 1.2084x over previous
//
#include <hip/hip_runtime.h>

namespace {
constexpr int CC = 3, FF = 51;
constexpr int BB = 4;
constexpr int HOUT = 384, WOUT = 384;
constexpr int HIN = 434, WIN = 434;
constexpr int KY = 4;                 // vertical outputs per thread
constexpr int LANES = 64;             // x-pixels per block
constexpr int NW = 4;                 // fx-split waves per block (13/13/13/12 taps)
constexpr int EXT = LANES + FF - 1;   // 114 valid f16 per channel strip
constexpr int LPAD = 128;             // strip pitch (f16), pow2 -> static indices
constexpr int NSG = CC * LPAD / LANES;   // 6 staged elems/lane
constexpr int NQW = 4;                // b64 LDS reads per (c, step)
constexpr int NPW = 8;                // f16 pairs per (t, step)
constexpr int SSTRIDE = NW * CC * LPAD;  // u16 elems per LDS buffer (1536)

using half2v = _Float16 __attribute__((ext_vector_type(2)));

// r4/r6-proven: __builtin_amdgcn_fdot2 emits v_dot2_f32_f16.
// (r5 lesson: hand-written VOP3P asm broke numerics — keep the builtin.)
__device__ __forceinline__ float fdot2f(half2v a, half2v b, float c) {
#if __has_builtin(__builtin_amdgcn_fdot2)
  return __builtin_amdgcn_fdot2(a, b, c, false);
#else
  return c + (float)a.x * (float)b.x + (float)a.y * (float)b.y;
#endif
}
}  // namespace

// Pure reg-staged kernel (NO global_load_lds anywhere: r10-r12 lesson — any
// DMA in the loop forces alias-conservative vmcnt(0) drains each step,
// nullifying ALL prefetch. Reg loads get precise register-counted vmcnt.)
// Ver values prefetched in 2-step groups (vvA/vvB, 8 regs each), issued
// ~2.5 compute-steps (~600+ cyc) ahead of consumption to cover HBM latency.
__global__ __launch_bounds__(NW* LANES, 2) void sepconv_kernel(
    const float* __restrict__ In, const float* __restrict__ Ver,
    const float* __restrict__ Hor, float* __restrict__ Out) {
  const int lane = threadIdx.x;
  const int w = threadIdx.y;          // fx-quarter
  const int x0 = blockIdx.x * LANES;
  const int y0 = blockIdx.y * KY;
  const int b = blockIdx.z;
  const int x = x0 + lane;
  const int fxBase = 13 * w;          // taps [fxBase, fxBase+ntaps)
  const int ntaps = (w < 3) ? 13 : 12;
  const int aw = (lane + fxBase) & 3;        // alignment class
  const int bw = lane + fxBase - aw;         // 4-f16-aligned strip base elem

  __shared__ __align__(16) unsigned short sIn[2][NW][CC][LPAD];
  __shared__ float sRed[NW - 1][CC][KY][LANES];
  unsigned short* const sflat = &sIn[0][0][0][0];

  const size_t HW = (size_t)HOUT * WOUT;

  // ---- per-pixel horizontal taps for this wave's fx range (OOB -> 0)
  half2v hp[KY][NPW];
  {
    const float* horx = Hor + (size_t)b * FF * HW + x;
#pragma unroll
    for (int t = 0; t < KY; ++t) {
      const float* hb = horx + (size_t)(y0 + t) * WOUT;
#pragma unroll
      for (int j = 0; j < NPW; ++j) {
        const int u0 = 2 * j - aw;
        const int u1 = u0 + 1;
        float f0 = (u0 >= 0 && u0 < ntaps) ? hb[(size_t)(fxBase + u0) * HW] : 0.0f;
        float f1 = (u1 >= 0 && u1 < ntaps) ? hb[(size_t)(fxBase + u1) * HW] : 0.0f;
        half2v p;
        p.x = (_Float16)f0;  // RTE
        p.y = (_Float16)f1;
        hp[t][j] = p;
      }
    }
  }

  const float* inb = In + ((size_t)b * CC * HIN + y0) * WIN + x0;
  const float* verb = Ver + (size_t)b * FF * HW + (size_t)y0 * WOUT + x;
  const float* vbase0 = Ver + (size_t)b * FF * HW + (size_t)(y0 + 0) * WOUT + x0;
  const float* vbase1 = Ver + (size_t)b * FF * HW + (size_t)(y0 + 1) * WOUT + x0;
  const float* vbase2 = Ver + (size_t)b * FF * HW + (size_t)(y0 + 2) * WOUT + x0;
  const float* vbase3 = Ver + (size_t)b * FF * HW + (size_t)(y0 + 3) * WOUT + x0;

  float acc[CC][KY] = {};
  float sv[NSG];
  float vvA[8], vvB[8];  // two 2-step Ver groups (16 regs total)

  // ---- In staging (r6-proven; register-tracked counted vmcnt) ----
#define STAGE_LOAD(R)                                                         \
  _Pragma("unroll") for (int k = 0; k < NSG; ++k) {                           \
    const int e = lane + (k & 1) * 64;                                        \
    const bool valid = ((k & 1) == 0) || (lane < EXT - LANES);                \
    sv[k] = valid ? inb[(size_t)((k >> 1) * HIN + (R)) * WIN + e] : 0.0f;     \
  }

#define STAGE_WRITE(BF)                                                       \
  _Pragma("unroll") for (int k = 0; k < NSG; ++k) {                           \
    const int e = lane + (k & 1) * 64;                                        \
    sflat[(BF)*SSTRIDE + (w * CC + (k >> 1)) * LPAD + e] =                    \
        __builtin_bit_cast(unsigned short, (_Float16)sv[k]);                  \
  }

  // ---- Ver prefetch: 2-step group, uniform bases (valid for 3<=R, R+1<=50)
#define VV_S2(R, VS)                                                          \
  _Pragma("unroll") for (int s = 0; s < 2; ++s) {                             \
    VS[4 * s + 0] = vbase0[(size_t)((R) + s - 0) * HW + lane];                \
    VS[4 * s + 1] = vbase1[(size_t)((R) + s - 1) * HW + lane];                \
    VS[4 * s + 2] = vbase2[(size_t)((R) + s - 2) * HW + lane];                \
    VS[4 * s + 3] = vbase3[(size_t)((R) + s - 3) * HW + lane];                \
  }

  // guarded single-step load into slot S (R compile-time -> guards fold)
#define VV_G1(R, VS, S)                                                       \
  _Pragma("unroll") for (int t = 0; t < KY; ++t) {                            \
    const int u = (R)-t;                                                      \
    VS[4 * (S) + t] = (u >= 0 && u < FF)                                      \
                          ? verb[(size_t)u * HW + (size_t)t * WOUT]           \
                          : 0.0f;                                             \
  }

  // ---- dot core for one step; vv = VS[4*S + t] (all static indices) ----
#define COMPUTE(BF, VS, S)                                                    \
  {                                                                           \
    _Pragma("unroll") for (int c = 0; c < CC; ++c) {                          \
      const unsigned short* rp = sflat + (BF)*SSTRIDE + (w * CC + c) * LPAD + bw; \
      float d[KY];                                                            \
      {                                                                       \
        const uint2 u2 = *reinterpret_cast<const uint2*>(rp);                 \
        const half2v p0 = __builtin_bit_cast(half2v, u2.x);                   \
        const half2v p1 = __builtin_bit_cast(half2v, u2.y);                   \
        _Pragma("unroll") for (int t = 0; t < KY; ++t) {                      \
          d[t] = fdot2f(p0, hp[t][0], 0.0f);                                  \
          d[t] = fdot2f(p1, hp[t][1], d[t]);                                  \
        }                                                                     \
      }                                                                       \
      _Pragma("unroll") for (int q = 1; q < NQW; ++q) {                       \
        const uint2 u2 = *reinterpret_cast<const uint2*>(rp + 4 * q);         \
        const half2v p0 = __builtin_bit_cast(half2v, u2.x);                   \
        const half2v p1 = __builtin_bit_cast(half2v, u2.y);                   \
        _Pragma("unroll") for (int t = 0; t < KY; ++t) {                      \
          d[t] = fdot2f(p0, hp[t][2 * q], d[t]);                              \
          d[t] = fdot2f(p1, hp[t][2 * q + 1], d[t]);                          \
        }                                                                     \
      }                                                                       \
      _Pragma("unroll") for (int t = 0; t < KY; ++t)                          \
        acc[c][t] = __builtin_fmaf(d[t], VS[4 * (S) + t], acc[c][t]);         \
    }                                                                         \
  }

  // ---- prologue: buf0 = row 0; vvA = steps 0,1; vvB = steps 2,3 ----
  STAGE_LOAD(0);
  STAGE_WRITE(0);
  VV_G1(0, vvA, 0); VV_G1(1, vvA, 1);
  VV_G1(2, vvB, 0); VV_G1(3, vvB, 1);

  // ---- steady: 4 steps/iter; each vv group re-issued ~2.5 steps before use
#pragma unroll 1
  for (int r = 0; r <= 40; r += 4) {
    STAGE_LOAD(r + 1); COMPUTE(0, vvA, 0); STAGE_WRITE(1);   // step r
    STAGE_LOAD(r + 2); COMPUTE(1, vvA, 1); STAGE_WRITE(0);   // step r+1
    VV_S2(r + 4, vvA);   // rows r+4,r+5 (max 44,45 — steady-valid)
    STAGE_LOAD(r + 3); COMPUTE(0, vvB, 0); STAGE_WRITE(1);   // step r+2
    STAGE_LOAD(r + 4); COMPUTE(1, vvB, 1); STAGE_WRITE(0);   // step r+3
    VV_S2(r + 6, vvB);   // rows r+6,r+7 (max 46,47 — steady-valid)
  }
  // after loop: steps 0..43 done; buf0 = row 44; vvA = 44,45; vvB = 46,47

  // ---- tail: steps 44..53 ----
  STAGE_LOAD(45); COMPUTE(0, vvA, 0); STAGE_WRITE(1);        // step 44
  STAGE_LOAD(46); COMPUTE(1, vvA, 1); STAGE_WRITE(0);        // step 45
  VV_S2(48, vvA);                                            // rows 48,49
  STAGE_LOAD(47); COMPUTE(0, vvB, 0); STAGE_WRITE(1);        // step 46
  STAGE_LOAD(48); COMPUTE(1, vvB, 1); STAGE_WRITE(0);        // step 47
  VV_G1(50, vvB, 0); VV_G1(51, vvB, 1);                      // rows 50,51
  STAGE_LOAD(49); COMPUTE(0, vvA, 0); STAGE_WRITE(1);        // step 48
  STAGE_LOAD(50); COMPUTE(1, vvA, 1); STAGE_WRITE(0);        // step 49
  VV_G1(52, vvA, 0); VV_G1(53, vvA, 1);                      // rows 52,53
  STAGE_LOAD(51); COMPUTE(0, vvB, 0); STAGE_WRITE(1);        // step 50
  STAGE_LOAD(52); COMPUTE(1, vvB, 1); STAGE_WRITE(0);        // step 51
  STAGE_LOAD(53); COMPUTE(0, vvA, 0); STAGE_WRITE(1);        // step 52
  COMPUTE(1, vvA, 1);                                        // step 53

  // ---- cross-wave fx reduction (4-way), then store
  if (w > 0) {
#pragma unroll
    for (int c = 0; c < CC; ++c)
#pragma unroll
      for (int t = 0; t < KY; ++t) sRed[w - 1][c][t][lane] = acc[c][t];
  }
  __syncthreads();
  if (w == 0) {
    float* outb = Out + (size_t)b * CC * HW + (size_t)y0 * WOUT + x0 + lane;
#pragma unroll
    for (int c = 0; c < CC; ++c)
#pragma unroll
      for (int t = 0; t < KY; ++t)
        outb[(size_t)c * HW + (size_t)t * WOUT] =
            acc[c][t] + sRed[0][c][t][lane] + sRed[1][c][t][lane] +
            sRed[2][c][t][lane];
  }
#undef STAGE_LOAD
#undef STAGE_WRITE
#undef VV_S2
#undef VV_G1
#undef COMPUTE
}

extern "C" void kernel_launch(void* const* d_in, const int* in_sizes, int n_in,
                              void* d_out, int out_size, void* d_ws, size_t ws_size,
                              hipStream_t stream) {
  const float* In = (const float*)d_in[0];
  const float* Ver = (const float*)d_in[1];
  const float* Hor = (const float*)d_in[2];
  float* Out = (float*)d_out;

  dim3 grid(WOUT / LANES, HOUT / KY, BB);
  dim3 block(LANES, NW, 1);
  sepconv_kernel<<<grid, block, 0, stream>>>(In, Ver, Hor, Out);
}

// Round 14
// 166.994 us; speedup vs baseline: 3.0092x; 2.4902x over previous
//
#include <hip/hip_runtime.h>

namespace {
constexpr int CC = 3, FF = 51;
constexpr int BB = 4;
constexpr int HOUT = 384, WOUT = 384;
constexpr int HIN = 434, WIN = 434;
constexpr int KY = 4;                 // vertical outputs per thread
constexpr int LANES = 64;             // x-pixels per block
constexpr int NW = 4;                 // fx-split waves per block (13/13/13/12 taps)
constexpr int EXT = LANES + FF - 1;   // 114 valid f16 per channel strip
constexpr int LPAD = 128;             // strip pitch (f16), pow2 -> static indices
constexpr int NSTEP = FF + KY - 1;    // 54 input rows per tile
constexpr int NSG = CC * LPAD / LANES;   // 6 staged elems/lane
constexpr int NQW = 4;                // b64 LDS reads per (c, step)
constexpr int NPW = 8;                // f16 pairs per (t, step)
constexpr int SSTRIDE = NW * CC * LPAD;  // u16 elems per LDS buffer (1536)

using half2v = _Float16 __attribute__((ext_vector_type(2)));

// r4/r6-proven: __builtin_amdgcn_fdot2 emits v_dot2_f32_f16.
// (r5 lesson: hand-written VOP3P asm broke numerics — keep the builtin.)
__device__ __forceinline__ float fdot2f(half2v a, half2v b, float c) {
#if __has_builtin(__builtin_amdgcn_fdot2)
  return __builtin_amdgcn_fdot2(a, b, c, false);
#else
  return c + (float)a.x * (float)b.x + (float)a.y * (float)b.y;
#endif
}
}  // namespace

// r6 body EXACTLY, with ONE change: the Ver (vv) load for step r+1 is issued
// BEFORE COMPUTE(r) into a second register set (vvA/vvB ping-pong, +4 VGPRs).
// r13 lesson: stay inside the ~12-reg headroom over r6's 52; tail reuses the
// same loop body via wave-uniform `more` branches (no unrolled tail macros).
// No global_load_lds anywhere (r10-r12: DMA forces per-step vmcnt(0) drains).
__global__ __launch_bounds__(NW* LANES, 2) void sepconv_kernel(
    const float* __restrict__ In, const float* __restrict__ Ver,
    const float* __restrict__ Hor, float* __restrict__ Out) {
  const int lane = threadIdx.x;
  const int w = threadIdx.y;          // fx-quarter
  const int x0 = blockIdx.x * LANES;
  const int y0 = blockIdx.y * KY;
  const int b = blockIdx.z;
  const int x = x0 + lane;
  const int fxBase = 13 * w;          // taps [fxBase, fxBase+ntaps)
  const int ntaps = (w < 3) ? 13 : 12;
  const int aw = (lane + fxBase) & 3;        // alignment class
  const int bw = lane + fxBase - aw;         // 4-f16-aligned strip base elem

  __shared__ __align__(16) unsigned short sIn[2][NW][CC][LPAD];
  __shared__ float sRed[NW - 1][CC][KY][LANES];
  unsigned short* const sflat = &sIn[0][0][0][0];

  const size_t HW = (size_t)HOUT * WOUT;

  // ---- per-pixel horizontal taps for this wave's fx range (OOB -> 0)
  half2v hp[KY][NPW];
  {
    const float* horx = Hor + (size_t)b * FF * HW + x;
#pragma unroll
    for (int t = 0; t < KY; ++t) {
      const float* hb = horx + (size_t)(y0 + t) * WOUT;
#pragma unroll
      for (int j = 0; j < NPW; ++j) {
        const int u0 = 2 * j - aw;
        const int u1 = u0 + 1;
        float f0 = (u0 >= 0 && u0 < ntaps) ? hb[(size_t)(fxBase + u0) * HW] : 0.0f;
        float f1 = (u1 >= 0 && u1 < ntaps) ? hb[(size_t)(fxBase + u1) * HW] : 0.0f;
        half2v p;
        p.x = (_Float16)f0;  // RTE
        p.y = (_Float16)f1;
        hp[t][j] = p;
      }
    }
  }

  const float* inb = In + ((size_t)b * CC * HIN + y0) * WIN + x0;
  const float* verb = Ver + (size_t)b * FF * HW + (size_t)y0 * WOUT + x;

  float acc[CC][KY] = {};
  float sv[NSG];
  float vvA[KY], vvB[KY];  // ping-pong Ver sets (+4 regs vs r6)

#define STAGE_LOAD(R)                                                         \
  _Pragma("unroll") for (int k = 0; k < NSG; ++k) {                           \
    const int e = lane + (k & 1) * 64;                                        \
    const bool valid = ((k & 1) == 0) || (lane < EXT - LANES);                \
    sv[k] = valid ? inb[(size_t)((k >> 1) * HIN + (R)) * WIN + e] : 0.0f;     \
  }

#define STAGE_WRITE(BF)                                                       \
  _Pragma("unroll") for (int k = 0; k < NSG; ++k) {                           \
    const int e = lane + (k & 1) * 64;                                        \
    sflat[(BF)*SSTRIDE + (w * CC + (k >> 1)) * LPAD + e] =                    \
        __builtin_bit_cast(unsigned short, (_Float16)sv[k]);                  \
  }

  // guarded Ver load for step R into register set V
#define VV_G(R, V)                                                            \
  _Pragma("unroll") for (int t = 0; t < KY; ++t) {                            \
    const int u = (R)-t;                                                      \
    V[t] = (u >= 0 && u < FF)                                                 \
               ? verb[(size_t)u * HW + (size_t)t * WOUT]                      \
               : 0.0f;                                                        \
  }

#define COMPUTE(BF, V)                                                        \
  {                                                                           \
    _Pragma("unroll") for (int c = 0; c < CC; ++c) {                          \
      const unsigned short* rp = sflat + (BF)*SSTRIDE + (w * CC + c) * LPAD + bw; \
      float d[KY];                                                            \
      {                                                                       \
        const uint2 u2 = *reinterpret_cast<const uint2*>(rp);                 \
        const half2v p0 = __builtin_bit_cast(half2v, u2.x);                   \
        const half2v p1 = __builtin_bit_cast(half2v, u2.y);                   \
        _Pragma("unroll") for (int t = 0; t < KY; ++t) {                      \
          d[t] = fdot2f(p0, hp[t][0], 0.0f);                                  \
          d[t] = fdot2f(p1, hp[t][1], d[t]);                                  \
        }                                                                     \
      }                                                                       \
      _Pragma("unroll") for (int q = 1; q < NQW; ++q) {                       \
        const uint2 u2 = *reinterpret_cast<const uint2*>(rp + 4 * q);         \
        const half2v p0 = __builtin_bit_cast(half2v, u2.x);                   \
        const half2v p1 = __builtin_bit_cast(half2v, u2.y);                   \
        _Pragma("unroll") for (int t = 0; t < KY; ++t) {                      \
          d[t] = fdot2f(p0, hp[t][2 * q], d[t]);                              \
          d[t] = fdot2f(p1, hp[t][2 * q + 1], d[t]);                          \
        }                                                                     \
      }                                                                       \
      _Pragma("unroll") for (int t = 0; t < KY; ++t)                          \
        acc[c][t] = __builtin_fmaf(d[t], V[t], acc[c][t]);                    \
    }                                                                         \
  }

  // ---- prologue: buf0 = row 0; vvA = step 0 ----
  STAGE_LOAD(0);
  STAGE_WRITE(0);
  VV_G(0, vvA);

  // ---- main loop (r6 structure + 1-step-ahead vv ping-pong) ----
#pragma unroll 1
  for (int r = 0; r < NSTEP; r += 2) {
    const bool more = (r + 2 < NSTEP);
    STAGE_LOAD(r + 1);          // In for step r+1 (T14: cover under COMPUTE r)
    VV_G(r + 1, vvB);           // Ver for step r+1 (cover under COMPUTE r)
    COMPUTE(0, vvA);            // step r
    STAGE_WRITE(1);
    if (more) {
      STAGE_LOAD(r + 2);        // In for step r+2
      VV_G(r + 2, vvA);         // Ver for step r+2 (cover under COMPUTE r+1)
    }
    COMPUTE(1, vvB);            // step r+1
    if (more) { STAGE_WRITE(0); }
  }

  // ---- cross-wave fx reduction (4-way), then store
  if (w > 0) {
#pragma unroll
    for (int c = 0; c < CC; ++c)
#pragma unroll
      for (int t = 0; t < KY; ++t) sRed[w - 1][c][t][lane] = acc[c][t];
  }
  __syncthreads();
  if (w == 0) {
    float* outb = Out + (size_t)b * CC * HW + (size_t)y0 * WOUT + x0 + lane;
#pragma unroll
    for (int c = 0; c < CC; ++c)
#pragma unroll
      for (int t = 0; t < KY; ++t)
        outb[(size_t)c * HW + (size_t)t * WOUT] =
            acc[c][t] + sRed[0][c][t][lane] + sRed[1][c][t][lane] +
            sRed[2][c][t][lane];
  }
#undef STAGE_LOAD
#undef STAGE_WRITE
#undef VV_G
#undef COMPUTE
}

extern "C" void kernel_launch(void* const* d_in, const int* in_sizes, int n_in,
                              void* d_out, int out_size, void* d_ws, size_t ws_size,
                              hipStream_t stream) {
  const float* In = (const float*)d_in[0];
  const float* Ver = (const float*)d_in[1];
  const float* Hor = (const float*)d_in[2];
  float* Out = (float*)d_out;

  dim3 grid(WOUT / LANES, HOUT / KY, BB);
  dim3 block(LANES, NW, 1);
  sepconv_kernel<<<grid, block, 0, stream>>>(In, Ver, Hor, Out);
}